// Round 8
// baseline (757.667 us; speedup 1.0000x reference)
//
#include <hip/hip_runtime.h>
#include <hip/hip_bf16.h>

#define N_TOK 16384
#define DIM   128
#define JT     64      // K/V tile (j) per iteration

#define KP 136         // kbuf row stride (shorts)
#define VP 68          // vbuf row stride (shorts)
#define PP 68          // pbuf row stride (shorts); 4 waves x 32 x 68 = 17408 B = kbuf size (aliased)

using bf16x8 = __attribute__((ext_vector_type(8))) short;   // 8 bf16 = 4 VGPRs (MFMA A/B frag)
using f32x4  = __attribute__((ext_vector_type(4))) float;   // MFMA C/D frag

static __device__ __forceinline__ unsigned short f2b(float f) {
    union { __hip_bfloat16 h; unsigned short u; } cv;
    cv.h = __float2bfloat16(f);   // RNE
    return cv.u;
}
static __device__ __forceinline__ float b2f(unsigned short s) {
    union { float f; unsigned u; } c; c.u = ((unsigned)s) << 16; return c.f;
}

// Load 8 consecutive fp32, round to bf16, pack as MFMA fragment half.
static __device__ __forceinline__ bf16x8 load8f(const float* p) {
    float4 a = *reinterpret_cast<const float4*>(p);
    float4 b = *reinterpret_cast<const float4*>(p + 4);
    bf16x8 r;
    r[0] = (short)f2b(a.x); r[1] = (short)f2b(a.y);
    r[2] = (short)f2b(a.z); r[3] = (short)f2b(a.w);
    r[4] = (short)f2b(b.x); r[5] = (short)f2b(b.y);
    r[6] = (short)f2b(b.z); r[7] = (short)f2b(b.w);
    return r;
}

// ---------------------------------------------------------------------------
// Marker: fill out with a diagnostic constant (host-side guard failures).
// ---------------------------------------------------------------------------
__global__ __launch_bounds__(256)
void marker_kernel(float* out, float val)
{
    int i = blockIdx.x * 256 + threadIdx.x;
    if (i < N_TOK * DIM) out[i] = val;
}

// ---------------------------------------------------------------------------
// QKV: Q = x@Wq^T, K = x@Wk^T, Vt = (x@Wv^T)^T.  fp32 in, bf16 out (ws).
// grid (N/64, 3), block 256. Wave handles 16 rows x 128 cols.
// MFMA 16x16x32 bf16: A[m=lane&15][k=quad*8+j], B[n=lane&15][k=quad*8+j],
// C/D: col=lane&15, row=quad*4+reg (m89-verified).
// ---------------------------------------------------------------------------
__global__ __launch_bounds__(256)
void qkv_kernel(const float* __restrict__ x,
                const float* __restrict__ wq,
                const float* __restrict__ wk,
                const float* __restrict__ wv,
                unsigned short* __restrict__ Q,
                unsigned short* __restrict__ K,
                unsigned short* __restrict__ Vt)
{
    const int t = threadIdx.x;
    const int wave = t >> 6, lane = t & 63;
    const int ln = lane & 15, quad = lane >> 4, q8 = quad * 8;
    const int z = blockIdx.y;
    const float* W = (z == 0) ? wq : (z == 1) ? wk : wv;
    const int r0 = blockIdx.x * 64 + wave * 16;

    bf16x8 a[4];
#pragma unroll
    for (int ks = 0; ks < 4; ++ks)
        a[ks] = load8f(&x[(size_t)(r0 + ln) * DIM + ks * 32 + q8]);

    f32x4 acc[8];
#pragma unroll
    for (int nt = 0; nt < 8; ++nt) acc[nt] = f32x4{0.f, 0.f, 0.f, 0.f};

#pragma unroll
    for (int nt = 0; nt < 8; ++nt)
#pragma unroll
        for (int ks = 0; ks < 4; ++ks) {
            bf16x8 b = load8f(&W[(size_t)(nt * 16 + ln) * DIM + ks * 32 + q8]);
            acc[nt] = __builtin_amdgcn_mfma_f32_16x16x32_bf16(a[ks], b, acc[nt], 0, 0, 0);
        }

#pragma unroll
    for (int nt = 0; nt < 8; ++nt) {
        const int col = nt * 16 + ln;
        if (z == 2) {
            // V transposed: Vt[d=col][n=row]; 4 consecutive rows -> one 8B store
            ushort4 v4;
            v4.x = f2b(acc[nt][0]); v4.y = f2b(acc[nt][1]);
            v4.z = f2b(acc[nt][2]); v4.w = f2b(acc[nt][3]);
            *reinterpret_cast<ushort4*>(&Vt[(size_t)col * N_TOK + r0 + quad * 4]) = v4;
        } else {
            unsigned short* dst = (z == 0) ? Q : K;
#pragma unroll
            for (int r = 0; r < 4; ++r)
                dst[(size_t)(r0 + quad * 4 + r) * DIM + col] = f2b(acc[nt][r]);
        }
    }
}

// ---------------------------------------------------------------------------
// Flash attention, fixed-offset softmax (exact: p = exp2(logit*log2e - 16),
// O = sum p*V, l = sum p, out = O/l; logits bounded so no running max).
// MT=2: 4 waves x 32 rows = 128 Q-rows/block. grid (N/128, nsplit).
// LDS aliasing: pbuf overlays kbuf (both 17408 B). Safe ordering:
//   stage -> B1 -> S reads kbuf -> B2 -> P writes (clobber kbuf) ->
//   lgkm drain -> PV reads pbuf+vbuf -> B3 -> next staging.
// LDS/block = 35072 B -> 4 blocks/CU = 16 waves/CU.
// Split mode: bf16 partial O + fp32 partial l (33.6 MB total at nsplit=8 --
// the volume round 6 proved L2-amplification-free).
// ---------------------------------------------------------------------------
__global__ __launch_bounds__(256, 4)
void flash_kernel(const unsigned short* __restrict__ Q,
                  const unsigned short* __restrict__ K,
                  const unsigned short* __restrict__ Vt,
                  const unsigned int* __restrict__ u32,
                  int jspan,
                  unsigned short* __restrict__ pOh, float* __restrict__ pl,
                  float* __restrict__ out)
{
    __shared__ unsigned short smem[64 * KP + DIM * VP];  // kbuf/pbuf union + vbuf
    __shared__ int ubuf[JT];

    unsigned short* kb = smem;                 // [64][KP]
    unsigned short* vb = smem + 64 * KP;       // [DIM][VP]

    const int t = threadIdx.x;
    const int wave = t >> 6, lane = t & 63;
    const int ln = lane & 15, quad = lane >> 4, q8 = quad * 8;
    const int r0 = blockIdx.x * 128 + wave * 32;
    const int split = blockIdx.y;
    const int j0 = split * jspan;
    const int j1 = j0 + jspan;

    unsigned short* pw = smem + wave * 32 * PP;   // wave's pbuf slice (aliases kbuf)

    const float lscale = 1.4426950408889634f * 0.08838834764831845f; // log2(e)/sqrt(128)
    const float cbias  = 5.0f * 1.4426950408889634f - 16.0f;         // same-user: 5*log2e - 16
    const float cnob   = -16.0f;                                     // different user

    // uid dtype sniff: identical verdict on every thread (uniform branch)
    bool i64 = true;
    for (int k = 0; k < 64; ++k) i64 = i64 && (u32[2 * k + 1] == 0u);

    bf16x8 qf[2][4];
    int uq[2][4];
#pragma unroll
    for (int mt = 0; mt < 2; ++mt) {
#pragma unroll
        for (int ks = 0; ks < 4; ++ks)
            qf[mt][ks] = *reinterpret_cast<const bf16x8*>(
                &Q[(size_t)(r0 + mt * 16 + ln) * DIM + ks * 32 + q8]);
#pragma unroll
        for (int r = 0; r < 4; ++r) {
            int i = r0 + mt * 16 + quad * 4 + r;
            uq[mt][r] = (int)(i64 ? u32[2 * i] : u32[i]);
        }
    }

    f32x4 o[2][8];
#pragma unroll
    for (int mt = 0; mt < 2; ++mt)
#pragma unroll
        for (int dt = 0; dt < 8; ++dt) o[mt][dt] = f32x4{0.f, 0.f, 0.f, 0.f};
    float lsum[2][4];
#pragma unroll
    for (int mt = 0; mt < 2; ++mt)
#pragma unroll
        for (int r = 0; r < 4; ++r) lsum[mt][r] = 0.f;

    for (int j = j0; j < j1; j += JT) {
        // ---- stage K tile (64x128) and Vt tile (128x64), 16B per lane ----
#pragma unroll
        for (int p = 0; p < 4; ++p) {
            int slot = p * 256 + t;
            int row = slot >> 4, seg = slot & 15;
            *reinterpret_cast<uint4*>(&kb[row * KP + seg * 8]) =
                *reinterpret_cast<const uint4*>(&K[(size_t)(j + row) * DIM + seg * 8]);
        }
#pragma unroll
        for (int p = 0; p < 4; ++p) {
            int slot = p * 256 + t;
            int row = slot >> 3, seg = slot & 7;
            *reinterpret_cast<uint4*>(&vb[row * VP + seg * 8]) =
                *reinterpret_cast<const uint4*>(&Vt[(size_t)row * N_TOK + j + seg * 8]);
        }
        if (t < JT) {
            int i = j + t;
            ubuf[t] = (int)(i64 ? u32[2 * i] : u32[i]);
        }
        __syncthreads();   // B1: staging visible

        // ---- S = Q @ K^T (2 x 16 rows x 64 cols per wave) ----
        f32x4 s[2][4];
#pragma unroll
        for (int mt = 0; mt < 2; ++mt)
#pragma unroll
            for (int nt = 0; nt < 4; ++nt) s[mt][nt] = f32x4{0.f, 0.f, 0.f, 0.f};
#pragma unroll
        for (int nt = 0; nt < 4; ++nt)
#pragma unroll
            for (int ks = 0; ks < 4; ++ks) {
                bf16x8 b = *reinterpret_cast<const bf16x8*>(&kb[(nt * 16 + ln) * KP + ks * 32 + q8]);
                s[0][nt] = __builtin_amdgcn_mfma_f32_16x16x32_bf16(qf[0][ks], b, s[0][nt], 0, 0, 0);
                s[1][nt] = __builtin_amdgcn_mfma_f32_16x16x32_bf16(qf[1][ks], b, s[1][nt], 0, 0, 0);
            }

        int uk[4];
#pragma unroll
        for (int nt = 0; nt < 4; ++nt) uk[nt] = ubuf[nt * 16 + ln];

        // ---- fixed-offset softmax into registers (no LDS writes yet) ----
#pragma unroll
        for (int mt = 0; mt < 2; ++mt)
#pragma unroll
            for (int r = 0; r < 4; ++r)
#pragma unroll
                for (int nt = 0; nt < 4; ++nt) {
                    float v = s[mt][nt][r] * lscale + (uq[mt][r] == uk[nt] ? cbias : cnob);
                    float p = exp2f(v);
                    lsum[mt][r] += p;
                    s[mt][nt][r] = p;
                }

        __syncthreads();   // B2: all S reads of kbuf complete -> safe to clobber

        // ---- P (C-layout) -> pbuf (aliases kbuf) for A-layout reload ----
#pragma unroll
        for (int mt = 0; mt < 2; ++mt)
#pragma unroll
            for (int r = 0; r < 4; ++r)
#pragma unroll
                for (int nt = 0; nt < 4; ++nt)
                    pw[(mt * 16 + quad * 4 + r) * PP + nt * 16 + ln] = f2b(s[mt][nt][r]);

        // pbuf slice is wave-private: drain own LDS writes before reads
        asm volatile("s_waitcnt lgkmcnt(0)" ::: "memory");

        // ---- O += P @ V ----
        bf16x8 pa[2][2];
#pragma unroll
        for (int mt = 0; mt < 2; ++mt)
#pragma unroll
            for (int k2 = 0; k2 < 2; ++k2)
                pa[mt][k2] = *reinterpret_cast<const bf16x8*>(&pw[(mt * 16 + ln) * PP + k2 * 32 + q8]);
#pragma unroll
        for (int dt = 0; dt < 8; ++dt)
#pragma unroll
            for (int k2 = 0; k2 < 2; ++k2) {
                bf16x8 b = *reinterpret_cast<const bf16x8*>(&vb[(dt * 16 + ln) * VP + k2 * 32 + q8]);
                o[0][dt] = __builtin_amdgcn_mfma_f32_16x16x32_bf16(pa[0][k2], b, o[0][dt], 0, 0, 0);
                o[1][dt] = __builtin_amdgcn_mfma_f32_16x16x32_bf16(pa[1][k2], b, o[1][dt], 0, 0, 0);
            }
        __syncthreads();   // B3: pbuf/vbuf reads done before next staging
    }

    // ---- epilogue: reduce l across the 16 lanes of each row ----
#pragma unroll
    for (int mt = 0; mt < 2; ++mt)
#pragma unroll
        for (int r = 0; r < 4; ++r) {
            float l = lsum[mt][r];
            l += __shfl_xor(l, 1, 64);
            l += __shfl_xor(l, 2, 64);
            l += __shfl_xor(l, 4, 64);
            l += __shfl_xor(l, 8, 64);
            lsum[mt][r] = l;
        }

    if (out != nullptr) {
        // direct: normalize, canary, store fp32
#pragma unroll
        for (int mt = 0; mt < 2; ++mt)
#pragma unroll
            for (int r = 0; r < 4; ++r) {
                float l = lsum[mt][r];
                bool lbad = !(l > 0.f) || !(l < 3.0e38f);
                float inv = 1.0f / l;
                int row = r0 + mt * 16 + quad * 4 + r;
#pragma unroll
                for (int dt = 0; dt < 8; ++dt) {
                    float v = o[mt][dt][r] * inv;
                    if (v != v) v = 12345.0f;
                    if (lbad)   v = 23456.0f;
                    out[(size_t)row * DIM + dt * 16 + ln] = v;
                }
            }
    } else {
        // split: bf16 unnormalized partial O + fp32 partial l (merge = sum)
        const size_t base = (size_t)split * N_TOK;
#pragma unroll
        for (int mt = 0; mt < 2; ++mt)
#pragma unroll
            for (int r = 0; r < 4; ++r) {
                int row = r0 + mt * 16 + quad * 4 + r;
#pragma unroll
                for (int dt = 0; dt < 8; ++dt)
                    pOh[(base + row) * DIM + dt * 16 + ln] = f2b(o[mt][dt][r]);
                if (ln == 0)
                    pl[base + row] = lsum[mt][r];
            }
    }
}

// ---------------------------------------------------------------------------
// Merge: out[row] = (sum_s pO[s][row]) / (sum_s pl[s][row]).  bf16 partials.
// block 256 = 4 waves = 4 rows; lane covers 2 cols (ushort2). grid N/4.
// ---------------------------------------------------------------------------
__global__ __launch_bounds__(256)
void merge_kernel(const unsigned short* __restrict__ pOh, const float* __restrict__ pl,
                  float* __restrict__ out, int ns)
{
    const int t = threadIdx.x;
    const int wave = t >> 6, lane = t & 63;
    const int row = blockIdx.x * 4 + wave;
    const int c = lane * 2;

    float l = 0.f;
    for (int s = 0; s < ns; ++s) l += pl[(size_t)s * N_TOK + row];
    bool lbad = !(l > 0.f) || !(l < 3.0e38f);
    float inv = 1.0f / l;

    float a0 = 0.f, a1 = 0.f;
    for (int s = 0; s < ns; ++s) {
        ushort2 v = *reinterpret_cast<const ushort2*>(
            &pOh[((size_t)s * N_TOK + row) * DIM + c]);
        a0 += b2f(v.x); a1 += b2f(v.y);
    }
    float v0 = a0 * inv, v1 = a1 * inv;
    if (v0 != v0) v0 = 12345.0f;
    if (v1 != v1) v1 = 12345.0f;
    if (lbad) { v0 = 23456.0f; v1 = 23456.0f; }
    float2 res; res.x = v0; res.y = v1;
    *reinterpret_cast<float2*>(&out[(size_t)row * DIM + c]) = res;
}

// ---------------------------------------------------------------------------
extern "C" void kernel_launch(void* const* d_in, const int* in_sizes, int n_in,
                              void* d_out, int out_size, void* d_ws, size_t ws_size,
                              hipStream_t stream)
{
    float* out = (float*)d_out;

    // Shape sanity: signature 5555 if the problem isn't what we assume.
    bool ok = (n_in == 5) &&
              in_sizes[0] == N_TOK * DIM && in_sizes[1] == N_TOK &&
              in_sizes[2] == DIM * DIM && in_sizes[3] == DIM * DIM &&
              in_sizes[4] == DIM * DIM && out_size == N_TOK * DIM;
    if (!ok) { marker_kernel<<<8192, 256, 0, stream>>>(out, 5555.f); return; }

    const float*        xf  = (const float*)d_in[0];
    const unsigned int* u32 = (const unsigned int*)d_in[1];
    const float*        wqf = (const float*)d_in[2];
    const float*        wkf = (const float*)d_in[3];
    const float*        wvf = (const float*)d_in[4];

    char* ws = (char*)d_ws;
    size_t off = 0;
    unsigned short* Q  = (unsigned short*)(ws + off); off += (size_t)N_TOK * DIM * 2;  // 4 MB
    unsigned short* K  = (unsigned short*)(ws + off); off += (size_t)N_TOK * DIM * 2;  // 4 MB
    unsigned short* Vt = (unsigned short*)(ws + off); off += (size_t)N_TOK * DIM * 2;  // 4 MB

    // Workspace sanity: signature 4444 if ws can't hold Q/K/Vt.
    if (ws_size < off) { marker_kernel<<<8192, 256, 0, stream>>>(out, 4444.f); return; }

    // Split-count selection: bf16 partial O + fp32 partial l per split.
    // nsplit=8 -> 1024 blocks = 4 blocks/CU co-resident (LDS 35072 B/block),
    // partials 33.6 MB -- the round-6-proven amplification-free volume.
    const size_t per_split = (size_t)N_TOK * DIM * 2 + (size_t)N_TOK * 4;
    int nsplit = 1;
    if (ws_size >= off + 8 * per_split)      nsplit = 8;
    else if (ws_size >= off + 4 * per_split) nsplit = 4;
    else if (ws_size >= off + 2 * per_split) nsplit = 2;

    qkv_kernel<<<dim3(N_TOK / 64, 3), 256, 0, stream>>>(xf, wqf, wkf, wvf, Q, K, Vt);

    if (nsplit >= 2) {
        unsigned short* pOh = (unsigned short*)(ws + off);
        float* pl = (float*)(ws + off + (size_t)nsplit * N_TOK * DIM * 2);
        flash_kernel<<<dim3(N_TOK / 128, nsplit), 256, 0, stream>>>(
            Q, K, Vt, u32, N_TOK / nsplit, pOh, pl, nullptr);
        merge_kernel<<<N_TOK / 4, 256, 0, stream>>>(pOh, pl, out, nsplit);
    } else {
        flash_kernel<<<dim3(N_TOK / 128, 1), 256, 0, stream>>>(
            Q, K, Vt, u32, N_TOK, nullptr, nullptr, out);
    }
}

// Round 9
// 656.230 us; speedup vs baseline: 1.1546x; 1.1546x over previous
//
#include <hip/hip_runtime.h>
#include <hip/hip_bf16.h>

#define N_TOK 16384
#define DIM   128
#define JT     64      // K/V tile (j) per iteration

#define KP 136         // kbuf row stride (shorts)
#define VP 68          // vbuf row stride (shorts)
#define PP 68          // pbuf row stride (shorts); 4 waves x 32 x 68 = 17408 B = kbuf size (aliased)

using bf16x8 = __attribute__((ext_vector_type(8))) short;   // 8 bf16 = 4 VGPRs (MFMA A/B frag)
using f32x4  = __attribute__((ext_vector_type(4))) float;   // MFMA C/D frag

static __device__ __forceinline__ unsigned short f2b(float f) {
    union { __hip_bfloat16 h; unsigned short u; } cv;
    cv.h = __float2bfloat16(f);   // RNE
    return cv.u;
}
static __device__ __forceinline__ float b2f(unsigned short s) {
    union { float f; unsigned u; } c; c.u = ((unsigned)s) << 16; return c.f;
}

// Load 8 consecutive fp32, round to bf16, pack as MFMA fragment half.
static __device__ __forceinline__ bf16x8 load8f(const float* p) {
    float4 a = *reinterpret_cast<const float4*>(p);
    float4 b = *reinterpret_cast<const float4*>(p + 4);
    bf16x8 r;
    r[0] = (short)f2b(a.x); r[1] = (short)f2b(a.y);
    r[2] = (short)f2b(a.z); r[3] = (short)f2b(a.w);
    r[4] = (short)f2b(b.x); r[5] = (short)f2b(b.y);
    r[6] = (short)f2b(b.z); r[7] = (short)f2b(b.w);
    return r;
}

// ---------------------------------------------------------------------------
// Marker: fill out with a diagnostic constant (host-side guard failures).
// ---------------------------------------------------------------------------
__global__ __launch_bounds__(256)
void marker_kernel(float* out, float val)
{
    int i = blockIdx.x * 256 + threadIdx.x;
    if (i < N_TOK * DIM) out[i] = val;
}

// ---------------------------------------------------------------------------
// QKV: Q = x@Wq^T, K = x@Wk^T, Vt = (x@Wv^T)^T.  fp32 in, bf16 out (ws).
// grid (N/64, 3), block 256. Wave handles 16 rows x 128 cols.
// MFMA 16x16x32 bf16: A[m=lane&15][k=quad*8+j], B[n=lane&15][k=quad*8+j],
// C/D: col=lane&15, row=quad*4+reg (m89-verified).
// ---------------------------------------------------------------------------
__global__ __launch_bounds__(256)
void qkv_kernel(const float* __restrict__ x,
                const float* __restrict__ wq,
                const float* __restrict__ wk,
                const float* __restrict__ wv,
                unsigned short* __restrict__ Q,
                unsigned short* __restrict__ K,
                unsigned short* __restrict__ Vt)
{
    const int t = threadIdx.x;
    const int wave = t >> 6, lane = t & 63;
    const int ln = lane & 15, quad = lane >> 4, q8 = quad * 8;
    const int z = blockIdx.y;
    const float* W = (z == 0) ? wq : (z == 1) ? wk : wv;
    const int r0 = blockIdx.x * 64 + wave * 16;

    bf16x8 a[4];
#pragma unroll
    for (int ks = 0; ks < 4; ++ks)
        a[ks] = load8f(&x[(size_t)(r0 + ln) * DIM + ks * 32 + q8]);

    f32x4 acc[8];
#pragma unroll
    for (int nt = 0; nt < 8; ++nt) acc[nt] = f32x4{0.f, 0.f, 0.f, 0.f};

#pragma unroll
    for (int nt = 0; nt < 8; ++nt)
#pragma unroll
        for (int ks = 0; ks < 4; ++ks) {
            bf16x8 b = load8f(&W[(size_t)(nt * 16 + ln) * DIM + ks * 32 + q8]);
            acc[nt] = __builtin_amdgcn_mfma_f32_16x16x32_bf16(a[ks], b, acc[nt], 0, 0, 0);
        }

#pragma unroll
    for (int nt = 0; nt < 8; ++nt) {
        const int col = nt * 16 + ln;
        if (z == 2) {
            // V transposed: Vt[d=col][n=row]; 4 consecutive rows -> one 8B store
            ushort4 v4;
            v4.x = f2b(acc[nt][0]); v4.y = f2b(acc[nt][1]);
            v4.z = f2b(acc[nt][2]); v4.w = f2b(acc[nt][3]);
            *reinterpret_cast<ushort4*>(&Vt[(size_t)col * N_TOK + r0 + quad * 4]) = v4;
        } else {
            unsigned short* dst = (z == 0) ? Q : K;
#pragma unroll
            for (int r = 0; r < 4; ++r)
                dst[(size_t)(r0 + quad * 4 + r) * DIM + col] = f2b(acc[nt][r]);
        }
    }
}

// ---------------------------------------------------------------------------
// Flash attention, fixed-offset softmax (exact: p = exp2(logit*log2e - 16),
// O = sum p*V, l = sum p, out = O/l; logits bounded so no running max).
// MT=2: 4 waves x 32 rows = 128 Q-rows/block. grid (N/128, nsplit).
// LDS aliasing: pbuf overlays kbuf (both 17408 B). Safe ordering:
//   stage -> B1 -> S reads kbuf -> B2 -> P writes (clobber kbuf) ->
//   lgkm drain -> PV reads pbuf+vbuf -> B3 -> next staging.
// LDS/block = 35328 B -> 4 blocks/CU (LDS-limited).
// __launch_bounds__(256,3): VGPR ~84 (r7-proven spill-free); (256,4) forced
// 64 VGPR -> 1.17 GB scratch spill traffic (r8 regression). Occupancy is
// then LDS-bound at 4 blocks/CU, not launch-bounds-bound.
// Split mode: bf16 partial O + fp32 partial l (33.6 MB at nsplit=8 --
// the round-6-proven L2-amplification-free volume).
// ---------------------------------------------------------------------------
__global__ __launch_bounds__(256, 3)
void flash_kernel(const unsigned short* __restrict__ Q,
                  const unsigned short* __restrict__ K,
                  const unsigned short* __restrict__ Vt,
                  const unsigned int* __restrict__ u32,
                  int jspan,
                  unsigned short* __restrict__ pOh, float* __restrict__ pl,
                  float* __restrict__ out)
{
    __shared__ unsigned short smem[64 * KP + DIM * VP];  // kbuf/pbuf union + vbuf
    __shared__ int ubuf[JT];

    unsigned short* kb = smem;                 // [64][KP]
    unsigned short* vb = smem + 64 * KP;       // [DIM][VP]

    const int t = threadIdx.x;
    const int wave = t >> 6, lane = t & 63;
    const int ln = lane & 15, quad = lane >> 4, q8 = quad * 8;
    const int r0 = blockIdx.x * 128 + wave * 32;
    const int split = blockIdx.y;
    const int j0 = split * jspan;
    const int j1 = j0 + jspan;

    unsigned short* pw = smem + wave * 32 * PP;   // wave's pbuf slice (aliases kbuf)

    const float lscale = 1.4426950408889634f * 0.08838834764831845f; // log2(e)/sqrt(128)
    const float cbias  = 5.0f * 1.4426950408889634f - 16.0f;         // same-user: 5*log2e - 16
    const float cnob   = -16.0f;                                     // different user

    // uid dtype sniff: identical verdict on every thread (uniform branch)
    bool i64 = true;
    for (int k = 0; k < 64; ++k) i64 = i64 && (u32[2 * k + 1] == 0u);

    bf16x8 qf[2][4];
    int uq[2][4];
#pragma unroll
    for (int mt = 0; mt < 2; ++mt) {
#pragma unroll
        for (int ks = 0; ks < 4; ++ks)
            qf[mt][ks] = *reinterpret_cast<const bf16x8*>(
                &Q[(size_t)(r0 + mt * 16 + ln) * DIM + ks * 32 + q8]);
#pragma unroll
        for (int r = 0; r < 4; ++r) {
            int i = r0 + mt * 16 + quad * 4 + r;
            uq[mt][r] = (int)(i64 ? u32[2 * i] : u32[i]);
        }
    }

    f32x4 o[2][8];
#pragma unroll
    for (int mt = 0; mt < 2; ++mt)
#pragma unroll
        for (int dt = 0; dt < 8; ++dt) o[mt][dt] = f32x4{0.f, 0.f, 0.f, 0.f};
    float lsum[2][4];
#pragma unroll
    for (int mt = 0; mt < 2; ++mt)
#pragma unroll
        for (int r = 0; r < 4; ++r) lsum[mt][r] = 0.f;

    for (int j = j0; j < j1; j += JT) {
        // ---- stage K tile (64x128) and Vt tile (128x64), 16B per lane ----
#pragma unroll
        for (int p = 0; p < 4; ++p) {
            int slot = p * 256 + t;
            int row = slot >> 4, seg = slot & 15;
            *reinterpret_cast<uint4*>(&kb[row * KP + seg * 8]) =
                *reinterpret_cast<const uint4*>(&K[(size_t)(j + row) * DIM + seg * 8]);
        }
#pragma unroll
        for (int p = 0; p < 4; ++p) {
            int slot = p * 256 + t;
            int row = slot >> 3, seg = slot & 7;
            *reinterpret_cast<uint4*>(&vb[row * VP + seg * 8]) =
                *reinterpret_cast<const uint4*>(&Vt[(size_t)row * N_TOK + j + seg * 8]);
        }
        if (t < JT) {
            int i = j + t;
            ubuf[t] = (int)(i64 ? u32[2 * i] : u32[i]);
        }
        __syncthreads();   // B1: staging visible

        // ---- S = Q @ K^T (2 x 16 rows x 64 cols per wave) ----
        f32x4 s[2][4];
#pragma unroll
        for (int mt = 0; mt < 2; ++mt)
#pragma unroll
            for (int nt = 0; nt < 4; ++nt) s[mt][nt] = f32x4{0.f, 0.f, 0.f, 0.f};
#pragma unroll
        for (int nt = 0; nt < 4; ++nt)
#pragma unroll
            for (int ks = 0; ks < 4; ++ks) {
                bf16x8 b = *reinterpret_cast<const bf16x8*>(&kb[(nt * 16 + ln) * KP + ks * 32 + q8]);
                s[0][nt] = __builtin_amdgcn_mfma_f32_16x16x32_bf16(qf[0][ks], b, s[0][nt], 0, 0, 0);
                s[1][nt] = __builtin_amdgcn_mfma_f32_16x16x32_bf16(qf[1][ks], b, s[1][nt], 0, 0, 0);
            }

        int uk[4];
#pragma unroll
        for (int nt = 0; nt < 4; ++nt) uk[nt] = ubuf[nt * 16 + ln];

        // ---- fixed-offset softmax into registers (no LDS writes yet) ----
#pragma unroll
        for (int mt = 0; mt < 2; ++mt)
#pragma unroll
            for (int r = 0; r < 4; ++r)
#pragma unroll
                for (int nt = 0; nt < 4; ++nt) {
                    float v = s[mt][nt][r] * lscale + (uq[mt][r] == uk[nt] ? cbias : cnob);
                    float p = exp2f(v);
                    lsum[mt][r] += p;
                    s[mt][nt][r] = p;
                }

        __syncthreads();   // B2: all S reads of kbuf complete -> safe to clobber

        // ---- P (C-layout) -> pbuf (aliases kbuf) for A-layout reload ----
#pragma unroll
        for (int mt = 0; mt < 2; ++mt)
#pragma unroll
            for (int r = 0; r < 4; ++r)
#pragma unroll
                for (int nt = 0; nt < 4; ++nt)
                    pw[(mt * 16 + quad * 4 + r) * PP + nt * 16 + ln] = f2b(s[mt][nt][r]);

        // pbuf slice is wave-private: drain own LDS writes before reads
        asm volatile("s_waitcnt lgkmcnt(0)" ::: "memory");

        // ---- O += P @ V ----
        bf16x8 pa[2][2];
#pragma unroll
        for (int mt = 0; mt < 2; ++mt)
#pragma unroll
            for (int k2 = 0; k2 < 2; ++k2)
                pa[mt][k2] = *reinterpret_cast<const bf16x8*>(&pw[(mt * 16 + ln) * PP + k2 * 32 + q8]);
#pragma unroll
        for (int dt = 0; dt < 8; ++dt)
#pragma unroll
            for (int k2 = 0; k2 < 2; ++k2) {
                bf16x8 b = *reinterpret_cast<const bf16x8*>(&vb[(dt * 16 + ln) * VP + k2 * 32 + q8]);
                o[0][dt] = __builtin_amdgcn_mfma_f32_16x16x32_bf16(pa[0][k2], b, o[0][dt], 0, 0, 0);
                o[1][dt] = __builtin_amdgcn_mfma_f32_16x16x32_bf16(pa[1][k2], b, o[1][dt], 0, 0, 0);
            }
        __syncthreads();   // B3: pbuf/vbuf reads done before next staging
    }

    // ---- epilogue: reduce l across the 16 lanes of each row ----
#pragma unroll
    for (int mt = 0; mt < 2; ++mt)
#pragma unroll
        for (int r = 0; r < 4; ++r) {
            float l = lsum[mt][r];
            l += __shfl_xor(l, 1, 64);
            l += __shfl_xor(l, 2, 64);
            l += __shfl_xor(l, 4, 64);
            l += __shfl_xor(l, 8, 64);
            lsum[mt][r] = l;
        }

    if (out != nullptr) {
        // direct: normalize, canary, store fp32
#pragma unroll
        for (int mt = 0; mt < 2; ++mt)
#pragma unroll
            for (int r = 0; r < 4; ++r) {
                float l = lsum[mt][r];
                bool lbad = !(l > 0.f) || !(l < 3.0e38f);
                float inv = 1.0f / l;
                int row = r0 + mt * 16 + quad * 4 + r;
#pragma unroll
                for (int dt = 0; dt < 8; ++dt) {
                    float v = o[mt][dt][r] * inv;
                    if (v != v) v = 12345.0f;
                    if (lbad)   v = 23456.0f;
                    out[(size_t)row * DIM + dt * 16 + ln] = v;
                }
            }
    } else {
        // split: bf16 unnormalized partial O + fp32 partial l (merge = sum)
        const size_t base = (size_t)split * N_TOK;
#pragma unroll
        for (int mt = 0; mt < 2; ++mt)
#pragma unroll
            for (int r = 0; r < 4; ++r) {
                int row = r0 + mt * 16 + quad * 4 + r;
#pragma unroll
                for (int dt = 0; dt < 8; ++dt)
                    pOh[(base + row) * DIM + dt * 16 + ln] = f2b(o[mt][dt][r]);
                if (ln == 0)
                    pl[base + row] = lsum[mt][r];
            }
    }
}

// ---------------------------------------------------------------------------
// Merge: out[row] = (sum_s pO[s][row]) / (sum_s pl[s][row]).  bf16 partials.
// block 256 = 4 waves = 4 rows; lane covers 2 cols (ushort2). grid N/4.
// ---------------------------------------------------------------------------
__global__ __launch_bounds__(256)
void merge_kernel(const unsigned short* __restrict__ pOh, const float* __restrict__ pl,
                  float* __restrict__ out, int ns)
{
    const int t = threadIdx.x;
    const int wave = t >> 6, lane = t & 63;
    const int row = blockIdx.x * 4 + wave;
    const int c = lane * 2;

    float l = 0.f;
    for (int s = 0; s < ns; ++s) l += pl[(size_t)s * N_TOK + row];
    bool lbad = !(l > 0.f) || !(l < 3.0e38f);
    float inv = 1.0f / l;

    float a0 = 0.f, a1 = 0.f;
    for (int s = 0; s < ns; ++s) {
        ushort2 v = *reinterpret_cast<const ushort2*>(
            &pOh[((size_t)s * N_TOK + row) * DIM + c]);
        a0 += b2f(v.x); a1 += b2f(v.y);
    }
    float v0 = a0 * inv, v1 = a1 * inv;
    if (v0 != v0) v0 = 12345.0f;
    if (v1 != v1) v1 = 12345.0f;
    if (lbad) { v0 = 23456.0f; v1 = 23456.0f; }
    float2 res; res.x = v0; res.y = v1;
    *reinterpret_cast<float2*>(&out[(size_t)row * DIM + c]) = res;
}

// ---------------------------------------------------------------------------
extern "C" void kernel_launch(void* const* d_in, const int* in_sizes, int n_in,
                              void* d_out, int out_size, void* d_ws, size_t ws_size,
                              hipStream_t stream)
{
    float* out = (float*)d_out;

    // Shape sanity: signature 5555 if the problem isn't what we assume.
    bool ok = (n_in == 5) &&
              in_sizes[0] == N_TOK * DIM && in_sizes[1] == N_TOK &&
              in_sizes[2] == DIM * DIM && in_sizes[3] == DIM * DIM &&
              in_sizes[4] == DIM * DIM && out_size == N_TOK * DIM;
    if (!ok) { marker_kernel<<<8192, 256, 0, stream>>>(out, 5555.f); return; }

    const float*        xf  = (const float*)d_in[0];
    const unsigned int* u32 = (const unsigned int*)d_in[1];
    const float*        wqf = (const float*)d_in[2];
    const float*        wkf = (const float*)d_in[3];
    const float*        wvf = (const float*)d_in[4];

    char* ws = (char*)d_ws;
    size_t off = 0;
    unsigned short* Q  = (unsigned short*)(ws + off); off += (size_t)N_TOK * DIM * 2;  // 4 MB
    unsigned short* K  = (unsigned short*)(ws + off); off += (size_t)N_TOK * DIM * 2;  // 4 MB
    unsigned short* Vt = (unsigned short*)(ws + off); off += (size_t)N_TOK * DIM * 2;  // 4 MB

    // Workspace sanity: signature 4444 if ws can't hold Q/K/Vt.
    if (ws_size < off) { marker_kernel<<<8192, 256, 0, stream>>>(out, 4444.f); return; }

    // Split-count selection: bf16 partial O + fp32 partial l per split.
    // nsplit=8 -> 1024 blocks feeds 4 blocks/CU (LDS 35328 B/block),
    // partials 33.6 MB -- round-6-proven amplification-free volume.
    const size_t per_split = (size_t)N_TOK * DIM * 2 + (size_t)N_TOK * 4;
    int nsplit = 1;
    if (ws_size >= off + 8 * per_split)      nsplit = 8;
    else if (ws_size >= off + 4 * per_split) nsplit = 4;
    else if (ws_size >= off + 2 * per_split) nsplit = 2;

    qkv_kernel<<<dim3(N_TOK / 64, 3), 256, 0, stream>>>(xf, wqf, wkf, wvf, Q, K, Vt);

    if (nsplit >= 2) {
        unsigned short* pOh = (unsigned short*)(ws + off);
        float* pl = (float*)(ws + off + (size_t)nsplit * N_TOK * DIM * 2);
        flash_kernel<<<dim3(N_TOK / 128, nsplit), 256, 0, stream>>>(
            Q, K, Vt, u32, N_TOK / nsplit, pOh, pl, nullptr);
        merge_kernel<<<N_TOK / 4, 256, 0, stream>>>(pOh, pl, out, nsplit);
    } else {
        flash_kernel<<<dim3(N_TOK / 128, 1), 256, 0, stream>>>(
            Q, K, Vt, u32, N_TOK, nullptr, nullptr, out);
    }
}

// Round 10
// 500.117 us; speedup vs baseline: 1.5150x; 1.3122x over previous
//
#include <hip/hip_runtime.h>
#include <hip/hip_bf16.h>

#define N_TOK 16384
#define DIM   128
#define JT     64      // K/V tile (j) per iteration

#define KP 136         // kbuf row stride (shorts)
#define VP 68          // vbuf row stride (shorts)
#define PP 68          // pbuf row stride (shorts)

using bf16x8 = __attribute__((ext_vector_type(8))) short;   // 8 bf16 = 4 VGPRs (MFMA A/B frag)
using f32x4  = __attribute__((ext_vector_type(4))) float;   // MFMA C/D frag

static __device__ __forceinline__ unsigned short f2b(float f) {
    union { __hip_bfloat16 h; unsigned short u; } cv;
    cv.h = __float2bfloat16(f);   // RNE
    return cv.u;
}
static __device__ __forceinline__ float b2f(unsigned short s) {
    union { float f; unsigned u; } c; c.u = ((unsigned)s) << 16; return c.f;
}

// Load 8 consecutive fp32, round to bf16, pack as MFMA fragment half.
static __device__ __forceinline__ bf16x8 load8f(const float* p) {
    float4 a = *reinterpret_cast<const float4*>(p);
    float4 b = *reinterpret_cast<const float4*>(p + 4);
    bf16x8 r;
    r[0] = (short)f2b(a.x); r[1] = (short)f2b(a.y);
    r[2] = (short)f2b(a.z); r[3] = (short)f2b(a.w);
    r[4] = (short)f2b(b.x); r[5] = (short)f2b(b.y);
    r[6] = (short)f2b(b.z); r[7] = (short)f2b(b.w);
    return r;
}

// ---------------------------------------------------------------------------
// Marker: fill out with a diagnostic constant (host-side guard failures).
// ---------------------------------------------------------------------------
__global__ __launch_bounds__(256)
void marker_kernel(float* out, float val)
{
    int i = blockIdx.x * 256 + threadIdx.x;
    if (i < N_TOK * DIM) out[i] = val;
}

// ---------------------------------------------------------------------------
// QKV: Q = x@Wq^T, K = x@Wk^T, Vt = (x@Wv^T)^T.  fp32 in, bf16 out (ws).
// grid (N/64, 3), block 256. Wave handles 16 rows x 128 cols.
// MFMA 16x16x32 bf16: A[m=lane&15][k=quad*8+j], B[n=lane&15][k=quad*8+j],
// C/D: col=lane&15, row=quad*4+reg (m89-verified).
// ---------------------------------------------------------------------------
__global__ __launch_bounds__(256)
void qkv_kernel(const float* __restrict__ x,
                const float* __restrict__ wq,
                const float* __restrict__ wk,
                const float* __restrict__ wv,
                unsigned short* __restrict__ Q,
                unsigned short* __restrict__ K,
                unsigned short* __restrict__ Vt)
{
    const int t = threadIdx.x;
    const int wave = t >> 6, lane = t & 63;
    const int ln = lane & 15, quad = lane >> 4, q8 = quad * 8;
    const int z = blockIdx.y;
    const float* W = (z == 0) ? wq : (z == 1) ? wk : wv;
    const int r0 = blockIdx.x * 64 + wave * 16;

    bf16x8 a[4];
#pragma unroll
    for (int ks = 0; ks < 4; ++ks)
        a[ks] = load8f(&x[(size_t)(r0 + ln) * DIM + ks * 32 + q8]);

    f32x4 acc[8];
#pragma unroll
    for (int nt = 0; nt < 8; ++nt) acc[nt] = f32x4{0.f, 0.f, 0.f, 0.f};

#pragma unroll
    for (int nt = 0; nt < 8; ++nt)
#pragma unroll
        for (int ks = 0; ks < 4; ++ks) {
            bf16x8 b = load8f(&W[(size_t)(nt * 16 + ln) * DIM + ks * 32 + q8]);
            acc[nt] = __builtin_amdgcn_mfma_f32_16x16x32_bf16(a[ks], b, acc[nt], 0, 0, 0);
        }

#pragma unroll
    for (int nt = 0; nt < 8; ++nt) {
        const int col = nt * 16 + ln;
        if (z == 2) {
            // V transposed: Vt[d=col][n=row]; 4 consecutive rows -> one 8B store
            ushort4 v4;
            v4.x = f2b(acc[nt][0]); v4.y = f2b(acc[nt][1]);
            v4.z = f2b(acc[nt][2]); v4.w = f2b(acc[nt][3]);
            *reinterpret_cast<ushort4*>(&Vt[(size_t)col * N_TOK + r0 + quad * 4]) = v4;
        } else {
            unsigned short* dst = (z == 0) ? Q : K;
#pragma unroll
            for (int r = 0; r < 4; ++r)
                dst[(size_t)(r0 + quad * 4 + r) * DIM + col] = f2b(acc[nt][r]);
        }
    }
}

// ---------------------------------------------------------------------------
// Flash attention, fixed-offset softmax (exact: p = exp2(logit*log2e - 16),
// O = sum p*V, l = sum p, out = O/l; logits bounded so no running max).
// MT=2: 4 waves x 32 rows = 128 Q-rows/block. grid (N/128, nsplit).
//
// Register budget (the r7-r9 lesson): unified VGPR+AGPR per wave must fit
// 512/min_waves. At (256,3): 170 regs. o=64 AGPR is fixed; so S tiles are
// processed in nt-PAIRS (s live = 16 AGPR, not 32): for each pair, MFMA both
// mt (kb-frags shared across mt), softmax, write P columns, free s.
// Peak: 64+16 AGPR + ~90 VGPR < 170 -> no scratch spill (r7/r9 spilled
// ~175-335MB/iter because o64+s32=96 AGPR > 86 available at (256,3)).
//
// pbuf separate (no aliasing): LDS = 52480 B -> 3 blocks/CU = 12 waves.
// 2 barriers/iter; pbuf is wave-private (lgkm drain only, r7-proven).
// ---------------------------------------------------------------------------
__global__ __launch_bounds__(256, 3)
void flash_kernel(const unsigned short* __restrict__ Q,
                  const unsigned short* __restrict__ K,
                  const unsigned short* __restrict__ Vt,
                  const unsigned int* __restrict__ u32,
                  int jspan,
                  unsigned short* __restrict__ pOh, float* __restrict__ pl,
                  float* __restrict__ out)
{
    __shared__ unsigned short kbuf[JT * KP];       // 17408 B
    __shared__ unsigned short vbuf[DIM * VP];      // 17408 B
    __shared__ unsigned short pbuf[4 * 32 * PP];   // 17408 B
    __shared__ int ubuf[JT];

    const int t = threadIdx.x;
    const int wave = t >> 6, lane = t & 63;
    const int ln = lane & 15, quad = lane >> 4, q8 = quad * 8;
    const int r0 = blockIdx.x * 128 + wave * 32;
    const int split = blockIdx.y;
    const int j0 = split * jspan;
    const int j1 = j0 + jspan;

    unsigned short* pw = &pbuf[wave * 32 * PP];    // wave-private P slice

    const float lscale = 1.4426950408889634f * 0.08838834764831845f; // log2(e)/sqrt(128)
    const float cbias  = 5.0f * 1.4426950408889634f - 16.0f;         // same-user: 5*log2e - 16
    const float cnob   = -16.0f;                                     // different user

    // uid dtype sniff: identical verdict on every thread (uniform branch)
    bool i64 = true;
    for (int k = 0; k < 64; ++k) i64 = i64 && (u32[2 * k + 1] == 0u);

    bf16x8 qf[2][4];
    int uq[2][4];
#pragma unroll
    for (int mt = 0; mt < 2; ++mt) {
#pragma unroll
        for (int ks = 0; ks < 4; ++ks)
            qf[mt][ks] = *reinterpret_cast<const bf16x8*>(
                &Q[(size_t)(r0 + mt * 16 + ln) * DIM + ks * 32 + q8]);
#pragma unroll
        for (int r = 0; r < 4; ++r) {
            int i = r0 + mt * 16 + quad * 4 + r;
            uq[mt][r] = (int)(i64 ? u32[2 * i] : u32[i]);
        }
    }

    f32x4 o[2][8];
#pragma unroll
    for (int mt = 0; mt < 2; ++mt)
#pragma unroll
        for (int dt = 0; dt < 8; ++dt) o[mt][dt] = f32x4{0.f, 0.f, 0.f, 0.f};
    float lsum[2][4];
#pragma unroll
    for (int mt = 0; mt < 2; ++mt)
#pragma unroll
        for (int r = 0; r < 4; ++r) lsum[mt][r] = 0.f;

    for (int j = j0; j < j1; j += JT) {
        // ---- stage K tile (64x128) and Vt tile (128x64), 16B per lane ----
#pragma unroll
        for (int p = 0; p < 4; ++p) {
            int slot = p * 256 + t;
            int row = slot >> 4, seg = slot & 15;
            *reinterpret_cast<uint4*>(&kbuf[row * KP + seg * 8]) =
                *reinterpret_cast<const uint4*>(&K[(size_t)(j + row) * DIM + seg * 8]);
        }
#pragma unroll
        for (int p = 0; p < 4; ++p) {
            int slot = p * 256 + t;
            int row = slot >> 3, seg = slot & 7;
            *reinterpret_cast<uint4*>(&vbuf[row * VP + seg * 8]) =
                *reinterpret_cast<const uint4*>(&Vt[(size_t)row * N_TOK + j + seg * 8]);
        }
        if (t < JT) {
            int i = j + t;
            ubuf[t] = (int)(i64 ? u32[2 * i] : u32[i]);
        }
        __syncthreads();   // B1: staging visible

        // ---- S + softmax + P-write in nt-PAIRS (s live = 16 AGPR max) ----
#pragma unroll
        for (int ntp = 0; ntp < 2; ++ntp) {
            f32x4 s[2][2];   // [mt][dn]
#pragma unroll
            for (int mt = 0; mt < 2; ++mt)
#pragma unroll
                for (int dn = 0; dn < 2; ++dn) s[mt][dn] = f32x4{0.f, 0.f, 0.f, 0.f};
#pragma unroll
            for (int ks = 0; ks < 4; ++ks)
#pragma unroll
                for (int dn = 0; dn < 2; ++dn) {
                    const int nt = ntp * 2 + dn;
                    bf16x8 b = *reinterpret_cast<const bf16x8*>(
                        &kbuf[(nt * 16 + ln) * KP + ks * 32 + q8]);
                    s[0][dn] = __builtin_amdgcn_mfma_f32_16x16x32_bf16(qf[0][ks], b, s[0][dn], 0, 0, 0);
                    s[1][dn] = __builtin_amdgcn_mfma_f32_16x16x32_bf16(qf[1][ks], b, s[1][dn], 0, 0, 0);
                }

#pragma unroll
            for (int dn = 0; dn < 2; ++dn) {
                const int nt = ntp * 2 + dn;
                const int uk = ubuf[nt * 16 + ln];
#pragma unroll
                for (int mt = 0; mt < 2; ++mt)
#pragma unroll
                    for (int r = 0; r < 4; ++r) {
                        float v = s[mt][dn][r] * lscale + (uq[mt][r] == uk ? cbias : cnob);
                        float p = exp2f(v);
                        lsum[mt][r] += p;
                        pw[(mt * 16 + quad * 4 + r) * PP + nt * 16 + ln] = f2b(p);
                    }
            }
        }

        // pbuf slice is wave-private: drain own LDS writes before reads
        asm volatile("s_waitcnt lgkmcnt(0)" ::: "memory");

        // ---- O += P @ V ----
        bf16x8 pa[2][2];
#pragma unroll
        for (int mt = 0; mt < 2; ++mt)
#pragma unroll
            for (int k2 = 0; k2 < 2; ++k2)
                pa[mt][k2] = *reinterpret_cast<const bf16x8*>(
                    &pw[(mt * 16 + ln) * PP + k2 * 32 + q8]);
#pragma unroll
        for (int dt = 0; dt < 8; ++dt)
#pragma unroll
            for (int k2 = 0; k2 < 2; ++k2) {
                bf16x8 b = *reinterpret_cast<const bf16x8*>(
                    &vbuf[(dt * 16 + ln) * VP + k2 * 32 + q8]);
                o[0][dt] = __builtin_amdgcn_mfma_f32_16x16x32_bf16(pa[0][k2], b, o[0][dt], 0, 0, 0);
                o[1][dt] = __builtin_amdgcn_mfma_f32_16x16x32_bf16(pa[1][k2], b, o[1][dt], 0, 0, 0);
            }
        __syncthreads();   // B2: kbuf/vbuf reads done before next staging
    }

    // ---- epilogue: reduce l across the 16 lanes of each row ----
#pragma unroll
    for (int mt = 0; mt < 2; ++mt)
#pragma unroll
        for (int r = 0; r < 4; ++r) {
            float l = lsum[mt][r];
            l += __shfl_xor(l, 1, 64);
            l += __shfl_xor(l, 2, 64);
            l += __shfl_xor(l, 4, 64);
            l += __shfl_xor(l, 8, 64);
            lsum[mt][r] = l;
        }

    if (out != nullptr) {
        // direct: normalize, canary, store fp32
#pragma unroll
        for (int mt = 0; mt < 2; ++mt)
#pragma unroll
            for (int r = 0; r < 4; ++r) {
                float l = lsum[mt][r];
                bool lbad = !(l > 0.f) || !(l < 3.0e38f);
                float inv = 1.0f / l;
                int row = r0 + mt * 16 + quad * 4 + r;
#pragma unroll
                for (int dt = 0; dt < 8; ++dt) {
                    float v = o[mt][dt][r] * inv;
                    if (v != v) v = 12345.0f;
                    if (lbad)   v = 23456.0f;
                    out[(size_t)row * DIM + dt * 16 + ln] = v;
                }
            }
    } else {
        // split: bf16 unnormalized partial O + fp32 partial l (merge = sum)
        const size_t base = (size_t)split * N_TOK;
#pragma unroll
        for (int mt = 0; mt < 2; ++mt)
#pragma unroll
            for (int r = 0; r < 4; ++r) {
                int row = r0 + mt * 16 + quad * 4 + r;
#pragma unroll
                for (int dt = 0; dt < 8; ++dt)
                    pOh[(base + row) * DIM + dt * 16 + ln] = f2b(o[mt][dt][r]);
                if (ln == 0)
                    pl[base + row] = lsum[mt][r];
            }
    }
}

// ---------------------------------------------------------------------------
// Merge: out[row] = (sum_s pO[s][row]) / (sum_s pl[s][row]).  bf16 partials.
// block 256 = 4 waves = 4 rows; lane covers 2 cols (ushort2). grid N/4.
// ---------------------------------------------------------------------------
__global__ __launch_bounds__(256)
void merge_kernel(const unsigned short* __restrict__ pOh, const float* __restrict__ pl,
                  float* __restrict__ out, int ns)
{
    const int t = threadIdx.x;
    const int wave = t >> 6, lane = t & 63;
    const int row = blockIdx.x * 4 + wave;
    const int c = lane * 2;

    float l = 0.f;
    for (int s = 0; s < ns; ++s) l += pl[(size_t)s * N_TOK + row];
    bool lbad = !(l > 0.f) || !(l < 3.0e38f);
    float inv = 1.0f / l;

    float a0 = 0.f, a1 = 0.f;
    for (int s = 0; s < ns; ++s) {
        ushort2 v = *reinterpret_cast<const ushort2*>(
            &pOh[((size_t)s * N_TOK + row) * DIM + c]);
        a0 += b2f(v.x); a1 += b2f(v.y);
    }
    float v0 = a0 * inv, v1 = a1 * inv;
    if (v0 != v0) v0 = 12345.0f;
    if (v1 != v1) v1 = 12345.0f;
    if (lbad) { v0 = 23456.0f; v1 = 23456.0f; }
    float2 res; res.x = v0; res.y = v1;
    *reinterpret_cast<float2*>(&out[(size_t)row * DIM + c]) = res;
}

// ---------------------------------------------------------------------------
extern "C" void kernel_launch(void* const* d_in, const int* in_sizes, int n_in,
                              void* d_out, int out_size, void* d_ws, size_t ws_size,
                              hipStream_t stream)
{
    float* out = (float*)d_out;

    // Shape sanity: signature 5555 if the problem isn't what we assume.
    bool ok = (n_in == 5) &&
              in_sizes[0] == N_TOK * DIM && in_sizes[1] == N_TOK &&
              in_sizes[2] == DIM * DIM && in_sizes[3] == DIM * DIM &&
              in_sizes[4] == DIM * DIM && out_size == N_TOK * DIM;
    if (!ok) { marker_kernel<<<8192, 256, 0, stream>>>(out, 5555.f); return; }

    const float*        xf  = (const float*)d_in[0];
    const unsigned int* u32 = (const unsigned int*)d_in[1];
    const float*        wqf = (const float*)d_in[2];
    const float*        wkf = (const float*)d_in[3];
    const float*        wvf = (const float*)d_in[4];

    char* ws = (char*)d_ws;
    size_t off = 0;
    unsigned short* Q  = (unsigned short*)(ws + off); off += (size_t)N_TOK * DIM * 2;  // 4 MB
    unsigned short* K  = (unsigned short*)(ws + off); off += (size_t)N_TOK * DIM * 2;  // 4 MB
    unsigned short* Vt = (unsigned short*)(ws + off); off += (size_t)N_TOK * DIM * 2;  // 4 MB

    // Workspace sanity: signature 4444 if ws can't hold Q/K/Vt.
    if (ws_size < off) { marker_kernel<<<8192, 256, 0, stream>>>(out, 4444.f); return; }

    // Split-count selection: bf16 partial O + fp32 partial l per split.
    // nsplit=8 -> 1024 blocks feeds 3 blocks/CU (LDS 52480 B/block).
    const size_t per_split = (size_t)N_TOK * DIM * 2 + (size_t)N_TOK * 4;
    int nsplit = 1;
    if (ws_size >= off + 8 * per_split)      nsplit = 8;
    else if (ws_size >= off + 4 * per_split) nsplit = 4;
    else if (ws_size >= off + 2 * per_split) nsplit = 2;

    qkv_kernel<<<dim3(N_TOK / 64, 3), 256, 0, stream>>>(xf, wqf, wkf, wvf, Q, K, Vt);

    if (nsplit >= 2) {
        unsigned short* pOh = (unsigned short*)(ws + off);
        float* pl = (float*)(ws + off + (size_t)nsplit * N_TOK * DIM * 2);
        flash_kernel<<<dim3(N_TOK / 128, nsplit), 256, 0, stream>>>(
            Q, K, Vt, u32, N_TOK / nsplit, pOh, pl, nullptr);
        merge_kernel<<<N_TOK / 4, 256, 0, stream>>>(pOh, pl, out, nsplit);
    } else {
        flash_kernel<<<dim3(N_TOK / 128, 1), 256, 0, stream>>>(
            Q, K, Vt, u32, N_TOK, nullptr, nullptr, out);
    }
}

// Round 11
// 356.203 us; speedup vs baseline: 2.1271x; 1.4040x over previous
//
#include <hip/hip_runtime.h>
#include <hip/hip_bf16.h>

#define N_TOK 16384
#define DIM   128
#define JT     64      // K/V tile (j) per iteration

#define KP 136         // kbuf row stride (shorts)
#define VP 68          // vbuf row stride (shorts)
#define PP 68          // pbuf row stride (shorts)

using bf16x8 = __attribute__((ext_vector_type(8))) short;   // 8 bf16 = 4 VGPRs (MFMA A/B frag)
using f32x4  = __attribute__((ext_vector_type(4))) float;   // MFMA C/D frag

static __device__ __forceinline__ unsigned short f2b(float f) {
    union { __hip_bfloat16 h; unsigned short u; } cv;
    cv.h = __float2bfloat16(f);   // RNE
    return cv.u;
}
static __device__ __forceinline__ float b2f(unsigned short s) {
    union { float f; unsigned u; } c; c.u = ((unsigned)s) << 16; return c.f;
}

// Load 8 consecutive fp32, round to bf16, pack as MFMA fragment half.
static __device__ __forceinline__ bf16x8 load8f(const float* p) {
    float4 a = *reinterpret_cast<const float4*>(p);
    float4 b = *reinterpret_cast<const float4*>(p + 4);
    bf16x8 r;
    r[0] = (short)f2b(a.x); r[1] = (short)f2b(a.y);
    r[2] = (short)f2b(a.z); r[3] = (short)f2b(a.w);
    r[4] = (short)f2b(b.x); r[5] = (short)f2b(b.y);
    r[6] = (short)f2b(b.z); r[7] = (short)f2b(b.w);
    return r;
}

// ---------------------------------------------------------------------------
// Marker: fill out with a diagnostic constant (host-side guard failures).
// ---------------------------------------------------------------------------
__global__ __launch_bounds__(256)
void marker_kernel(float* out, float val)
{
    int i = blockIdx.x * 256 + threadIdx.x;
    if (i < N_TOK * DIM) out[i] = val;
}

// ---------------------------------------------------------------------------
// QKV: Q = x@Wq^T, K = x@Wk^T, Vt = (x@Wv^T)^T.  fp32 in, bf16 out (ws).
// grid (N/64, 3), block 256. Wave handles 16 rows x 128 cols.
// MFMA 16x16x32 bf16: A[m=lane&15][k=quad*8+j], B[n=lane&15][k=quad*8+j],
// C/D: col=lane&15, row=quad*4+reg (m89-verified).
// ---------------------------------------------------------------------------
__global__ __launch_bounds__(256)
void qkv_kernel(const float* __restrict__ x,
                const float* __restrict__ wq,
                const float* __restrict__ wk,
                const float* __restrict__ wv,
                unsigned short* __restrict__ Q,
                unsigned short* __restrict__ K,
                unsigned short* __restrict__ Vt)
{
    const int t = threadIdx.x;
    const int wave = t >> 6, lane = t & 63;
    const int ln = lane & 15, quad = lane >> 4, q8 = quad * 8;
    const int z = blockIdx.y;
    const float* W = (z == 0) ? wq : (z == 1) ? wk : wv;
    const int r0 = blockIdx.x * 64 + wave * 16;

    bf16x8 a[4];
#pragma unroll
    for (int ks = 0; ks < 4; ++ks)
        a[ks] = load8f(&x[(size_t)(r0 + ln) * DIM + ks * 32 + q8]);

    f32x4 acc[8];
#pragma unroll
    for (int nt = 0; nt < 8; ++nt) acc[nt] = f32x4{0.f, 0.f, 0.f, 0.f};

#pragma unroll
    for (int nt = 0; nt < 8; ++nt)
#pragma unroll
        for (int ks = 0; ks < 4; ++ks) {
            bf16x8 b = load8f(&W[(size_t)(nt * 16 + ln) * DIM + ks * 32 + q8]);
            acc[nt] = __builtin_amdgcn_mfma_f32_16x16x32_bf16(a[ks], b, acc[nt], 0, 0, 0);
        }

#pragma unroll
    for (int nt = 0; nt < 8; ++nt) {
        const int col = nt * 16 + ln;
        if (z == 2) {
            // V transposed: Vt[d=col][n=row]; 4 consecutive rows -> one 8B store
            ushort4 v4;
            v4.x = f2b(acc[nt][0]); v4.y = f2b(acc[nt][1]);
            v4.z = f2b(acc[nt][2]); v4.w = f2b(acc[nt][3]);
            *reinterpret_cast<ushort4*>(&Vt[(size_t)col * N_TOK + r0 + quad * 4]) = v4;
        } else {
            unsigned short* dst = (z == 0) ? Q : K;
#pragma unroll
            for (int r = 0; r < 4; ++r)
                dst[(size_t)(r0 + quad * 4 + r) * DIM + col] = f2b(acc[nt][r]);
        }
    }
}

// ---------------------------------------------------------------------------
// Flash attention, fixed-offset softmax (exact: p = exp2(logit*log2e - 16),
// O = sum p*V, l = sum p, out = O/l; logits bounded so no running max).
// MT=2: 4 waves x 32 rows = 128 Q-rows/block. grid (N/128, nsplit).
//
// REGISTER LESSON (r6-r10): every __launch_bounds__(256, >=3) build spilled
// (WRITE_SIZE 147MB-1.17GB scratch); only (256,2) builds are spill-free.
// The 2nd arg is an ALLOCATOR floor, not a scheduler cap: with (256,2) the
// compiler has a 256-reg budget (no spill), actual usage ~124-150 unified,
// and the HW still co-schedules 3 blocks/CU because the limiter is LDS
// (52736 B <= 160K/3), not the launch bound.
//
// nt-PAIR S processing keeps live AGPRs at o(64)+s(16)=80 instead of 96.
// pbuf separate (no aliasing): 2 barriers/iter; pbuf is wave-private
// (lgkm drain only, r7-proven correct).
// ---------------------------------------------------------------------------
__global__ __launch_bounds__(256, 2)
void flash_kernel(const unsigned short* __restrict__ Q,
                  const unsigned short* __restrict__ K,
                  const unsigned short* __restrict__ Vt,
                  const unsigned int* __restrict__ u32,
                  int jspan,
                  unsigned short* __restrict__ pOh, float* __restrict__ pl,
                  float* __restrict__ out)
{
    __shared__ unsigned short kbuf[JT * KP];       // 17408 B
    __shared__ unsigned short vbuf[DIM * VP];      // 17408 B
    __shared__ unsigned short pbuf[4 * 32 * PP];   // 17408 B
    __shared__ int ubuf[JT];

    const int t = threadIdx.x;
    const int wave = t >> 6, lane = t & 63;
    const int ln = lane & 15, quad = lane >> 4, q8 = quad * 8;
    const int r0 = blockIdx.x * 128 + wave * 32;
    const int split = blockIdx.y;
    const int j0 = split * jspan;
    const int j1 = j0 + jspan;

    unsigned short* pw = &pbuf[wave * 32 * PP];    // wave-private P slice

    const float lscale = 1.4426950408889634f * 0.08838834764831845f; // log2(e)/sqrt(128)
    const float cbias  = 5.0f * 1.4426950408889634f - 16.0f;         // same-user: 5*log2e - 16
    const float cnob   = -16.0f;                                     // different user

    // uid dtype sniff: identical verdict on every thread (uniform branch)
    bool i64 = true;
    for (int k = 0; k < 64; ++k) i64 = i64 && (u32[2 * k + 1] == 0u);

    bf16x8 qf[2][4];
    int uq[2][4];
#pragma unroll
    for (int mt = 0; mt < 2; ++mt) {
#pragma unroll
        for (int ks = 0; ks < 4; ++ks)
            qf[mt][ks] = *reinterpret_cast<const bf16x8*>(
                &Q[(size_t)(r0 + mt * 16 + ln) * DIM + ks * 32 + q8]);
#pragma unroll
        for (int r = 0; r < 4; ++r) {
            int i = r0 + mt * 16 + quad * 4 + r;
            uq[mt][r] = (int)(i64 ? u32[2 * i] : u32[i]);
        }
    }

    f32x4 o[2][8];
#pragma unroll
    for (int mt = 0; mt < 2; ++mt)
#pragma unroll
        for (int dt = 0; dt < 8; ++dt) o[mt][dt] = f32x4{0.f, 0.f, 0.f, 0.f};
    float lsum[2][4];
#pragma unroll
    for (int mt = 0; mt < 2; ++mt)
#pragma unroll
        for (int r = 0; r < 4; ++r) lsum[mt][r] = 0.f;

    for (int j = j0; j < j1; j += JT) {
        // ---- stage K tile (64x128) and Vt tile (128x64), 16B per lane ----
#pragma unroll
        for (int p = 0; p < 4; ++p) {
            int slot = p * 256 + t;
            int row = slot >> 4, seg = slot & 15;
            *reinterpret_cast<uint4*>(&kbuf[row * KP + seg * 8]) =
                *reinterpret_cast<const uint4*>(&K[(size_t)(j + row) * DIM + seg * 8]);
        }
#pragma unroll
        for (int p = 0; p < 4; ++p) {
            int slot = p * 256 + t;
            int row = slot >> 3, seg = slot & 7;
            *reinterpret_cast<uint4*>(&vbuf[row * VP + seg * 8]) =
                *reinterpret_cast<const uint4*>(&Vt[(size_t)row * N_TOK + j + seg * 8]);
        }
        if (t < JT) {
            int i = j + t;
            ubuf[t] = (int)(i64 ? u32[2 * i] : u32[i]);
        }
        __syncthreads();   // B1: staging visible

        // ---- S + softmax + P-write in nt-PAIRS (s live = 16 AGPR max) ----
#pragma unroll
        for (int ntp = 0; ntp < 2; ++ntp) {
            f32x4 s[2][2];   // [mt][dn]
#pragma unroll
            for (int mt = 0; mt < 2; ++mt)
#pragma unroll
                for (int dn = 0; dn < 2; ++dn) s[mt][dn] = f32x4{0.f, 0.f, 0.f, 0.f};
#pragma unroll
            for (int ks = 0; ks < 4; ++ks)
#pragma unroll
                for (int dn = 0; dn < 2; ++dn) {
                    const int nt = ntp * 2 + dn;
                    bf16x8 b = *reinterpret_cast<const bf16x8*>(
                        &kbuf[(nt * 16 + ln) * KP + ks * 32 + q8]);
                    s[0][dn] = __builtin_amdgcn_mfma_f32_16x16x32_bf16(qf[0][ks], b, s[0][dn], 0, 0, 0);
                    s[1][dn] = __builtin_amdgcn_mfma_f32_16x16x32_bf16(qf[1][ks], b, s[1][dn], 0, 0, 0);
                }

#pragma unroll
            for (int dn = 0; dn < 2; ++dn) {
                const int nt = ntp * 2 + dn;
                const int uk = ubuf[nt * 16 + ln];
#pragma unroll
                for (int mt = 0; mt < 2; ++mt)
#pragma unroll
                    for (int r = 0; r < 4; ++r) {
                        float v = s[mt][dn][r] * lscale + (uq[mt][r] == uk ? cbias : cnob);
                        float p = exp2f(v);
                        lsum[mt][r] += p;
                        pw[(mt * 16 + quad * 4 + r) * PP + nt * 16 + ln] = f2b(p);
                    }
            }
        }

        // pbuf slice is wave-private: drain own LDS writes before reads
        asm volatile("s_waitcnt lgkmcnt(0)" ::: "memory");

        // ---- O += P @ V ----
        bf16x8 pa[2][2];
#pragma unroll
        for (int mt = 0; mt < 2; ++mt)
#pragma unroll
            for (int k2 = 0; k2 < 2; ++k2)
                pa[mt][k2] = *reinterpret_cast<const bf16x8*>(
                    &pw[(mt * 16 + ln) * PP + k2 * 32 + q8]);
#pragma unroll
        for (int dt = 0; dt < 8; ++dt)
#pragma unroll
            for (int k2 = 0; k2 < 2; ++k2) {
                bf16x8 b = *reinterpret_cast<const bf16x8*>(
                    &vbuf[(dt * 16 + ln) * VP + k2 * 32 + q8]);
                o[0][dt] = __builtin_amdgcn_mfma_f32_16x16x32_bf16(pa[0][k2], b, o[0][dt], 0, 0, 0);
                o[1][dt] = __builtin_amdgcn_mfma_f32_16x16x32_bf16(pa[1][k2], b, o[1][dt], 0, 0, 0);
            }
        __syncthreads();   // B2: kbuf/vbuf reads done before next staging
    }

    // ---- epilogue: reduce l across the 16 lanes of each row ----
#pragma unroll
    for (int mt = 0; mt < 2; ++mt)
#pragma unroll
        for (int r = 0; r < 4; ++r) {
            float l = lsum[mt][r];
            l += __shfl_xor(l, 1, 64);
            l += __shfl_xor(l, 2, 64);
            l += __shfl_xor(l, 4, 64);
            l += __shfl_xor(l, 8, 64);
            lsum[mt][r] = l;
        }

    if (out != nullptr) {
        // direct: normalize, canary, store fp32
#pragma unroll
        for (int mt = 0; mt < 2; ++mt)
#pragma unroll
            for (int r = 0; r < 4; ++r) {
                float l = lsum[mt][r];
                bool lbad = !(l > 0.f) || !(l < 3.0e38f);
                float inv = 1.0f / l;
                int row = r0 + mt * 16 + quad * 4 + r;
#pragma unroll
                for (int dt = 0; dt < 8; ++dt) {
                    float v = o[mt][dt][r] * inv;
                    if (v != v) v = 12345.0f;
                    if (lbad)   v = 23456.0f;
                    out[(size_t)row * DIM + dt * 16 + ln] = v;
                }
            }
    } else {
        // split: bf16 unnormalized partial O + fp32 partial l (merge = sum)
        const size_t base = (size_t)split * N_TOK;
#pragma unroll
        for (int mt = 0; mt < 2; ++mt)
#pragma unroll
            for (int r = 0; r < 4; ++r) {
                int row = r0 + mt * 16 + quad * 4 + r;
#pragma unroll
                for (int dt = 0; dt < 8; ++dt)
                    pOh[(base + row) * DIM + dt * 16 + ln] = f2b(o[mt][dt][r]);
                if (ln == 0)
                    pl[base + row] = lsum[mt][r];
            }
    }
}

// ---------------------------------------------------------------------------
// Merge: out[row] = (sum_s pO[s][row]) / (sum_s pl[s][row]).  bf16 partials.
// block 256 = 4 waves = 4 rows; lane covers 2 cols (ushort2). grid N/4.
// ---------------------------------------------------------------------------
__global__ __launch_bounds__(256)
void merge_kernel(const unsigned short* __restrict__ pOh, const float* __restrict__ pl,
                  float* __restrict__ out, int ns)
{
    const int t = threadIdx.x;
    const int wave = t >> 6, lane = t & 63;
    const int row = blockIdx.x * 4 + wave;
    const int c = lane * 2;

    float l = 0.f;
    for (int s = 0; s < ns; ++s) l += pl[(size_t)s * N_TOK + row];
    bool lbad = !(l > 0.f) || !(l < 3.0e38f);
    float inv = 1.0f / l;

    float a0 = 0.f, a1 = 0.f;
    for (int s = 0; s < ns; ++s) {
        ushort2 v = *reinterpret_cast<const ushort2*>(
            &pOh[((size_t)s * N_TOK + row) * DIM + c]);
        a0 += b2f(v.x); a1 += b2f(v.y);
    }
    float v0 = a0 * inv, v1 = a1 * inv;
    if (v0 != v0) v0 = 12345.0f;
    if (v1 != v1) v1 = 12345.0f;
    if (lbad) { v0 = 23456.0f; v1 = 23456.0f; }
    float2 res; res.x = v0; res.y = v1;
    *reinterpret_cast<float2*>(&out[(size_t)row * DIM + c]) = res;
}

// ---------------------------------------------------------------------------
extern "C" void kernel_launch(void* const* d_in, const int* in_sizes, int n_in,
                              void* d_out, int out_size, void* d_ws, size_t ws_size,
                              hipStream_t stream)
{
    float* out = (float*)d_out;

    // Shape sanity: signature 5555 if the problem isn't what we assume.
    bool ok = (n_in == 5) &&
              in_sizes[0] == N_TOK * DIM && in_sizes[1] == N_TOK &&
              in_sizes[2] == DIM * DIM && in_sizes[3] == DIM * DIM &&
              in_sizes[4] == DIM * DIM && out_size == N_TOK * DIM;
    if (!ok) { marker_kernel<<<8192, 256, 0, stream>>>(out, 5555.f); return; }

    const float*        xf  = (const float*)d_in[0];
    const unsigned int* u32 = (const unsigned int*)d_in[1];
    const float*        wqf = (const float*)d_in[2];
    const float*        wkf = (const float*)d_in[3];
    const float*        wvf = (const float*)d_in[4];

    char* ws = (char*)d_ws;
    size_t off = 0;
    unsigned short* Q  = (unsigned short*)(ws + off); off += (size_t)N_TOK * DIM * 2;  // 4 MB
    unsigned short* K  = (unsigned short*)(ws + off); off += (size_t)N_TOK * DIM * 2;  // 4 MB
    unsigned short* Vt = (unsigned short*)(ws + off); off += (size_t)N_TOK * DIM * 2;  // 4 MB

    // Workspace sanity: signature 4444 if ws can't hold Q/K/Vt.
    if (ws_size < off) { marker_kernel<<<8192, 256, 0, stream>>>(out, 4444.f); return; }

    // Split-count selection: bf16 partial O + fp32 partial l per split.
    // nsplit=8 -> 1024 blocks feeds 3 blocks/CU (LDS 52736 B/block).
    const size_t per_split = (size_t)N_TOK * DIM * 2 + (size_t)N_TOK * 4;
    int nsplit = 1;
    if (ws_size >= off + 8 * per_split)      nsplit = 8;
    else if (ws_size >= off + 4 * per_split) nsplit = 4;
    else if (ws_size >= off + 2 * per_split) nsplit = 2;

    qkv_kernel<<<dim3(N_TOK / 64, 3), 256, 0, stream>>>(xf, wqf, wkf, wvf, Q, K, Vt);

    if (nsplit >= 2) {
        unsigned short* pOh = (unsigned short*)(ws + off);
        float* pl = (float*)(ws + off + (size_t)nsplit * N_TOK * DIM * 2);
        flash_kernel<<<dim3(N_TOK / 128, nsplit), 256, 0, stream>>>(
            Q, K, Vt, u32, N_TOK / nsplit, pOh, pl, nullptr);
        merge_kernel<<<N_TOK / 4, 256, 0, stream>>>(pOh, pl, out, nsplit);
    } else {
        flash_kernel<<<dim3(N_TOK / 128, 1), 256, 0, stream>>>(
            Q, K, Vt, u32, N_TOK, nullptr, nullptr, out);
    }
}